// Round 10
// baseline (267.255 us; speedup 1.0000x reference)
//
#include <hip/hip_runtime.h>
#include <hip/hip_bf16.h>

// Problem constants (B=2, S=2048, H=768, NH=12, HS=64)
#define BATCH 2
#define SEQ   2048
#define HID   768
#define NH    12
#define HS    64
#define MROWS (BATCH*SEQ)   // 4096
#define N3    (3*HID)       // 2304
#define HB    (NH*BATCH)    // 24
#define NBLK_GEMM 576       // (N3/128)*(MROWS/128)

typedef __attribute__((ext_vector_type(8))) short short8;
typedef __attribute__((ext_vector_type(4))) float floatx4;

// logits in log2 domain: Q pre-scaled by 0.125*log2(e) in GEMM epilogue
#define QSCALE 0.1803368801111204f

__device__ __forceinline__ unsigned short f2bf(float x){
  __hip_bfloat16 h = __float2bfloat16(x);
  return __builtin_bit_cast(unsigned short, h);
}
__device__ __forceinline__ unsigned int f2bf2(float lo, float hi){
  return (unsigned int)f2bf(lo) | ((unsigned int)f2bf(hi) << 16);
}
// pack two POSITIVE floats to bf16x2 with round-half-up: 2 adds + 1 v_perm
__device__ __forceinline__ unsigned int f2bf2_rhu(float lo, float hi){
  unsigned int a = __builtin_bit_cast(unsigned int, lo) + 0x8000u;
  unsigned int b = __builtin_bit_cast(unsigned int, hi) + 0x8000u;
  return __builtin_amdgcn_perm(b, a, 0x07060302u);  // [b.hi16 : a.hi16]
}
// async global->LDS, 16B per lane. LDS dest must be wave-uniform base + lane*16.
__device__ __forceinline__ void glds16(const unsigned short* g, unsigned short* l){
  __builtin_amdgcn_global_load_lds(
    (const __attribute__((address_space(1))) unsigned int*)g,
    (__attribute__((address_space(3))) unsigned int*)l, 16, 0, 0);
}

// ---------- fused convert + QKV projection GEMM ----------
// Phase 1: all 576 blocks convert X/Wq/Wk/Wv fp32->bf16 (grid-stride);
//          block 0 also builds maskadd + per-tile mask bitmask.
// Device barrier (all blocks resident: launch_bounds(256,3) => >=768 slots).
// Phase 2: 128x128 GEMM, BK=32, dbuf async LDS staging, swizzled; epilogues
//          write Qb/Kb [hb][s][64] (Q pre-scaled) and Vtb [hb][64][s].
__global__ __launch_bounds__(256, 3) void qkv_fused_kernel(
    const float* __restrict__ X,
    const float* __restrict__ Wq, const float* __restrict__ Wk, const float* __restrict__ Wv,
    const int* __restrict__ mask,
    const float* __restrict__ bq, const float* __restrict__ bk, const float* __restrict__ bv,
    unsigned short* __restrict__ Xb,   // [4096][768] bf16
    unsigned short* __restrict__ Wb,   // [2304][768] bf16
    unsigned short* __restrict__ Qb, unsigned short* __restrict__ Kb,
    unsigned short* __restrict__ Vtb,
    float* __restrict__ maskaddG, unsigned int* __restrict__ flagsG,
    unsigned int* __restrict__ bar)
{
  const int tid = threadIdx.x;
  const int bid = blockIdx.y * gridDim.x + blockIdx.x;   // 0..575

  // ---------------- phase 1: convert ----------------
  {
    const int XQ = MROWS*HID/4;     // 786432 float4 quads in X
    const int WQ = HID*HID/4;       // 147456 per weight
    const int TOT = XQ + 3*WQ;      // 1228800
    for(int i = bid*256 + tid; i < TOT; i += NBLK_GEMM*256){
      const float* src; unsigned short* dst; int off;
      if(i < XQ){ src = X; dst = Xb; off = i; }
      else {
        int j = i - XQ;
        int w = j / WQ; off = j - w*WQ;
        src = (w==0) ? Wq : (w==1) ? Wk : Wv;
        dst = Wb + (size_t)w*HID*HID;
      }
      float4 v = reinterpret_cast<const float4*>(src)[off];
      ushort4 o;
      o.x = f2bf(v.x); o.y = f2bf(v.y); o.z = f2bf(v.z); o.w = f2bf(v.w);
      reinterpret_cast<ushort4*>(dst)[off] = o;
    }
    if(bid == 0){
      for(int i=tid;i<BATCH*SEQ;i+=256) maskaddG[i] = mask[i] ? 0.f : -1e30f;
      if(tid < 2) flagsG[tid] = 0u;
      __syncthreads();
      if(tid < BATCH*32){
        int b = tid >> 5, t = tid & 31;
        const int* mrow = mask + b*SEQ + t*64;
        int any = 0;
        for(int i=0;i<64;i++) any |= (mrow[i]==0);
        if(any) atomicOr(&flagsG[b], 1u << t);
      }
    }
  }

  // ---------------- device barrier (all 576 blocks resident) ----------------
  __syncthreads();                        // all waves' stores issued & drained
  if(tid == 0){
    __threadfence();                      // agent-scope release (wbL2)
    __hip_atomic_fetch_add(bar, 1u, __ATOMIC_RELEASE, __HIP_MEMORY_SCOPE_AGENT);
    while(__hip_atomic_load(bar, __ATOMIC_ACQUIRE, __HIP_MEMORY_SCOPE_AGENT) < NBLK_GEMM)
      __builtin_amdgcn_s_sleep(2);
    __threadfence();                      // agent-scope acquire (invL1/L2)
  }
  __syncthreads();

  // ---------------- phase 2: GEMM ----------------
  __shared__ __align__(16) union {
    struct { unsigned short A[2][128][32]; unsigned short B[2][128][32]; } s; // 32 KB
    unsigned short T[4][64][72];                                             // 36 KB (epilogue)
  } u;
  const int m0 = blockIdx.y << 7;
  const int n0 = blockIdx.x << 7;
  const int wave = tid >> 6, lane = tid & 63;
  const int wr = wave >> 1, wc = wave & 1;
  const int quad = lane >> 4, l15 = lane & 15;

  const unsigned short* gsrc[4];
  unsigned short* ldst[4];
  #pragma unroll
  for(int p=0;p<4;p++){
    int ck  = ((p&1)<<8) + tid;            // 0..511
    int row = ck>>2, c = ck&3, pc = c ^ (row&3);
    if(p<2){ gsrc[p] = Xb + (size_t)(m0+row)*HID + (pc<<3); ldst[p] = &u.s.A[0][row][c<<3]; }
    else   { gsrc[p] = Wb + (size_t)(n0+row)*HID + (pc<<3); ldst[p] = &u.s.B[0][row][c<<3]; }
  }

  floatx4 acc[4][4];
  #pragma unroll
  for(int i=0;i<4;i++)
    #pragma unroll
    for(int j=0;j<4;j++) acc[i][j] = (floatx4){0.f,0.f,0.f,0.f};

  auto stage = [&](int buf, int k0){
    const int bo = buf*(128*32);
    #pragma unroll
    for(int p=0;p<4;p++) glds16(gsrc[p] + k0, ldst[p] + bo);
  };

  stage(0, 0);
  __syncthreads();

  const int swa = l15 & 3;
  for(int t=0;t<HID/32;t++){
    const int buf = t & 1;
    if(t < HID/32 - 1) stage(buf^1, (t+1)*32);
    short8 a[4], b[4];
    #pragma unroll
    for(int i=0;i<4;i++)
      a[i] = *reinterpret_cast<const short8*>(&u.s.A[buf][wr*64+i*16+l15][(quad^swa)<<3]);
    #pragma unroll
    for(int j=0;j<4;j++)
      b[j] = *reinterpret_cast<const short8*>(&u.s.B[buf][wc*64+j*16+l15][(quad^swa)<<3]);
    #pragma unroll
    for(int i=0;i<4;i++)
      #pragma unroll
      for(int j=0;j<4;j++)
        acc[i][j] = __builtin_amdgcn_mfma_f32_16x16x32_bf16(a[i], b[j], acc[i][j], 0, 0, 0);
    __syncthreads();
  }

  // ---- epilogue; C layout col=lane&15 (n), row=quad*4+reg (m) ----
  const int which = n0 / HID;
  const int nbase = n0 - which*HID + wc*64;
  const int head  = nbase >> 6;
  const int b_    = m0 >> 11;
  const int hb    = head*BATCH + b_;
  const int s0    = (m0 & 2047) + wr*64;
  if(which < 2){
    unsigned short* dst = which==0 ? Qb : Kb;
    const float* bias = which==0 ? bq : bk;
    const float scale = which==0 ? QSCALE : 1.0f;
    #pragma unroll
    for(int j=0;j<4;j++){
      const float bb = bias[nbase + j*16 + l15];
      #pragma unroll
      for(int i=0;i<4;i++)
        #pragma unroll
        for(int r=0;r<4;r++)
          u.T[wave][i*16 + quad*4 + r][j*16 + l15] = f2bf((acc[i][j][r] + bb)*scale);
    }
    #pragma unroll
    for(int p=0;p<8;p++){
      const int row = p*8 + (lane>>3), dc = (lane&7)*8;
      uint4 v = *reinterpret_cast<const uint4*>(&u.T[wave][row][dc]);
      *reinterpret_cast<uint4*>(dst + ((size_t)(hb<<11) + s0 + row)*HS + dc) = v;
    }
  } else {
    #pragma unroll
    for(int j=0;j<4;j++){
      const float bb = bv[nbase + j*16 + l15];
      #pragma unroll
      for(int i=0;i<4;i++){
        uint2 pk;
        pk.x = f2bf2(acc[i][j][0]+bb, acc[i][j][1]+bb);
        pk.y = f2bf2(acc[i][j][2]+bb, acc[i][j][3]+bb);
        *reinterpret_cast<uint2*>(&u.T[wave][j*16+l15][i*16 + quad*4]) = pk;  // T[d][m]
      }
    }
    #pragma unroll
    for(int p=0;p<8;p++){
      const int d = p*8 + (lane>>3), cm = lane & 7;
      uint4 v = *reinterpret_cast<const uint4*>(&u.T[wave][d][cm*8]);
      *reinterpret_cast<uint4*>(Vtb + ((size_t)(hb*HS) + d)*SEQ + s0 + cm*8) = v;
    }
  }
}

// ---------- flash attention (R7 structure): no-max softmax, S^T, K+V LDS dbuf ----------
// grid HB*32; 64 q rows/block, 4 waves x 16 q rows; 1 barrier per 64-key tile;
// swizzled conflict-free LDS; packed-P via stride-68 Ps (b64 ops); rhu pack.
__global__ __launch_bounds__(256) void attn_kernel(
    const unsigned short* __restrict__ Qb,   // [hb][2048][64] (pre-scaled, log2 domain)
    const unsigned short* __restrict__ Kb,   // [hb][2048][64]
    const unsigned short* __restrict__ Vtb,  // [hb][64][2048]
    const float* __restrict__ maskaddG,      // [B][2048]
    const unsigned int* __restrict__ flagsG, // [B] bitmask of masked 64-key tiles
    float* __restrict__ out)                 // [B][2048][768]
{
  __shared__ __align__(16) unsigned short Ks2 [2][64][64];  // 16 KB
  __shared__ __align__(16) unsigned short Vts2[2][64][64];  // 16 KB
  __shared__ __align__(16) unsigned short Ps2 [4][16][68];  // 8.5 KB

  const int bid = blockIdx.x;
  const int hb = bid >> 5, qt = bid & 31, q0 = qt << 6;
  const int tid = threadIdx.x, wave = tid >> 6, lane = tid & 63;
  const int quad = lane >> 4, l15 = lane & 15;
  const int b_ = hb & 1, head = hb >> 1;

  // staging descriptors (chunk = p*256+tid; row=ck/8, c=ck%8, swizzle c^(row&7))
  const unsigned short* gK[2]; const unsigned short* gV[2];
  unsigned short* lK[2]; unsigned short* lV[2];
  #pragma unroll
  for(int p=0;p<2;p++){
    int ck = (p<<8) + tid;
    int row = ck>>3, c = ck&7, pc = c ^ (row&7);
    gK[p] = Kb  + ((size_t)(hb<<11) + row)*HS + (pc<<3);
    lK[p] = &Ks2[0][row][c<<3];
    gV[p] = Vtb + ((size_t)(hb*HS) + row)*SEQ + (pc<<3);
    lV[p] = &Vts2[0][row][c<<3];
  }
  auto stage = [&](int buf, int k0){
    const int bo = buf*(64*64);
    #pragma unroll
    for(int p=0;p<2;p++){
      glds16(gK[p] + (size_t)k0*HS, lK[p] + bo);
      glds16(gV[p] + k0,           lV[p] + bo);
    }
  };

  stage(0, 0);                               // async prefetch tile 0

  // Q fragments: direct b128 loads (scale folded in by GEMM)
  short8 a_q[2];
  {
    const unsigned short* qsrc = Qb + ((size_t)(hb<<11) + q0 + wave*16 + l15)*HS;
    a_q[0] = *reinterpret_cast<const short8*>(qsrc + quad*8);
    a_q[1] = *reinterpret_cast<const short8*>(qsrc + 32 + quad*8);
  }
  const unsigned int fl = flagsG[b_];        // per-tile masked bits, loaded ONCE

  float lsum4[4] = {0.f,0.f,0.f,0.f};
  floatx4 o_acc[4];
  #pragma unroll
  for(int dt=0;dt<4;dt++) o_acc[dt] = (floatx4){0.f,0.f,0.f,0.f};

  __syncthreads();                           // tile 0 staged

  const int sw = l15 & 7;
  for(int t=0;t<SEQ/64;t++){
    const int buf = t & 1, k0 = t << 6;
    if(t < SEQ/64 - 1) stage(buf^1, k0 + 64);   // async prefetch next tile

    const unsigned short (*Kst)[64] = Ks2[buf];
    const unsigned short (*Vst)[64] = Vts2[buf];

    // S^T: rows = keys (quad*4+r), cols = queries (l15)
    floatx4 st[4];
    #pragma unroll
    for(int kt=0;kt<4;kt++){
      st[kt] = (floatx4){0.f,0.f,0.f,0.f};
      #pragma unroll
      for(int c=0;c<2;c++){
        short8 kf = *reinterpret_cast<const short8*>(
            &Kst[kt*16 + l15][(((c<<2)+quad)^sw)<<3]);
        st[kt] = __builtin_amdgcn_mfma_f32_16x16x32_bf16(kf, a_q[c], st[kt], 0, 0, 0);
      }
    }

    // P = exp2(S [+ mask]); rhu-pack pairs; write P[q=l15][key] (2x b64)
    const bool masked = (fl >> t) & 1u;      // wave-uniform
    #pragma unroll
    for(int kt=0;kt<4;kt++){
      float p0,p1,p2,p3;
      if(!masked){
        p0 = exp2f(st[kt][0]); p1 = exp2f(st[kt][1]);
        p2 = exp2f(st[kt][2]); p3 = exp2f(st[kt][3]);
      } else {
        float4 ma = *reinterpret_cast<const float4*>(
            maskaddG + (b_<<11) + k0 + kt*16 + quad*4);
        p0 = exp2f(st[kt][0] + ma.x); p1 = exp2f(st[kt][1] + ma.y);
        p2 = exp2f(st[kt][2] + ma.z); p3 = exp2f(st[kt][3] + ma.w);
      }
      lsum4[0] += p0; lsum4[1] += p1; lsum4[2] += p2; lsum4[3] += p3;
      uint2 pk;
      pk.x = f2bf2_rhu(p0, p1);
      pk.y = f2bf2_rhu(p2, p3);
      *reinterpret_cast<uint2*>(&Ps2[wave][l15][kt*16 + quad*4]) = pk;
    }

    // A-frag read (same-wave RAW via lgkmcnt), then O += P V
    short8 ap0, ap1;
    {
      unsigned long long x0 = *reinterpret_cast<const unsigned long long*>(&Ps2[wave][l15][quad*8]);
      unsigned long long x1 = *reinterpret_cast<const unsigned long long*>(&Ps2[wave][l15][quad*8 + 4]);
      unsigned long long y0 = *reinterpret_cast<const unsigned long long*>(&Ps2[wave][l15][32 + quad*8]);
      unsigned long long y1 = *reinterpret_cast<const unsigned long long*>(&Ps2[wave][l15][32 + quad*8 + 4]);
      union { unsigned long long u[2]; short8 s; } cv0, cv1;
      cv0.u[0] = x0; cv0.u[1] = x1;
      cv1.u[0] = y0; cv1.u[1] = y1;
      ap0 = cv0.s; ap1 = cv1.s;
    }
    #pragma unroll
    for(int dt=0;dt<4;dt++){
      short8 bv0 = *reinterpret_cast<const short8*>(&Vst[dt*16 + l15][(quad^sw)<<3]);
      short8 bv1 = *reinterpret_cast<const short8*>(&Vst[dt*16 + l15][((4+quad)^sw)<<3]);
      o_acc[dt] = __builtin_amdgcn_mfma_f32_16x16x32_bf16(ap0, bv0, o_acc[dt], 0, 0, 0);
      o_acc[dt] = __builtin_amdgcn_mfma_f32_16x16x32_bf16(ap1, bv1, o_acc[dt], 0, 0, 0);
    }
    __syncthreads();   // staged t+1 drained; everyone done reading buf
  }

  // per-query row sum: lane holds q=l15 partial; reduce across quads, redistribute
  float lsum = (lsum4[0]+lsum4[1]) + (lsum4[2]+lsum4[3]);
  lsum += __shfl_xor(lsum, 16);
  lsum += __shfl_xor(lsum, 32);
  float linv[4];
  #pragma unroll
  for(int r=0;r<4;r++) linv[r] = 1.0f / __shfl(lsum, quad*4 + r);

  #pragma unroll
  for(int dt=0;dt<4;dt++){
    #pragma unroll
    for(int r=0;r<4;r++){
      const int srow = q0 + wave*16 + quad*4 + r;
      out[((size_t)(b_<<11) + srow)*HID + (head<<6) + dt*16 + l15] =
        o_acc[dt][r] * linv[r];
    }
  }
}

extern "C" void kernel_launch(void* const* d_in, const int* in_sizes, int n_in,
                              void* d_out, int out_size, void* d_ws, size_t ws_size,
                              hipStream_t stream) {
  const float* X    = (const float*)d_in[0];
  const int*   mask = (const int*)  d_in[1];
  const float* Wq   = (const float*)d_in[2];
  const float* bq   = (const float*)d_in[3];
  const float* Wk   = (const float*)d_in[4];
  const float* bk   = (const float*)d_in[5];
  const float* Wv   = (const float*)d_in[6];
  const float* bv   = (const float*)d_in[7];
  float* out = (float*)d_out;

  char* ws = (char*)d_ws;
  unsigned short* Xb  = (unsigned short*)ws;
  unsigned short* Wb  = Xb  + (size_t)MROWS*HID;
  unsigned short* Qb  = Wb  + (size_t)N3*HID;
  unsigned short* Kb  = Qb  + (size_t)HB*SEQ*HS;
  unsigned short* Vtb = Kb  + (size_t)HB*SEQ*HS;
  float* maskaddG = (float*)(Vtb + (size_t)HB*SEQ*HS);
  unsigned int* flagsG = (unsigned int*)(maskaddG + MROWS);  // 2 uints
  unsigned int* bar    = (unsigned int*)(((uintptr_t)(flagsG + 2) + 63) & ~(uintptr_t)63);

  // barrier counter must start at 0 every launch (ws is re-poisoned to 0xAA)
  hipMemsetAsync(bar, 0, 64, stream);

  qkv_fused_kernel<<<dim3(N3/128, MROWS/128), 256, 0, stream>>>(
      X, Wq, Wk, Wv, mask, bq, bk, bv,
      Xb, Wb, Qb, Kb, Vtb, maskaddG, flagsG, bar);

  attn_kernel<<<HB*32, 256, 0, stream>>>(
      Qb, Kb, Vtb, maskaddG, flagsG, out);
}

// Round 11
// 163.220 us; speedup vs baseline: 1.6374x; 1.6374x over previous
//
#include <hip/hip_runtime.h>
#include <hip/hip_bf16.h>

// Problem constants (B=2, S=2048, H=768, NH=12, HS=64)
#define BATCH 2
#define SEQ   2048
#define HID   768
#define NH    12
#define HS    64
#define MROWS (BATCH*SEQ)   // 4096
#define N3    (3*HID)       // 2304
#define HB    (NH*BATCH)    // 24

typedef __attribute__((ext_vector_type(8))) short short8;
typedef __attribute__((ext_vector_type(4))) float floatx4;

// logits in log2 domain: Q pre-scaled by 0.125*log2(e) in GEMM epilogue
#define QSCALE 0.1803368801111204f

__device__ __forceinline__ unsigned short f2bf(float x){
  __hip_bfloat16 h = __float2bfloat16(x);
  return __builtin_bit_cast(unsigned short, h);
}
__device__ __forceinline__ unsigned int f2bf2(float lo, float hi){
  return (unsigned int)f2bf(lo) | ((unsigned int)f2bf(hi) << 16);
}
// pack two POSITIVE floats to bf16x2 with round-half-up: 2 adds + 1 v_perm
__device__ __forceinline__ unsigned int f2bf2_rhu(float lo, float hi){
  unsigned int a = __builtin_bit_cast(unsigned int, lo) + 0x8000u;
  unsigned int b = __builtin_bit_cast(unsigned int, hi) + 0x8000u;
  return __builtin_amdgcn_perm(b, a, 0x07060302u);  // [b.hi16 : a.hi16]
}
// raw v_exp_f32 (exp2): our domain needs no OCML edge-case expansion
__device__ __forceinline__ float fast_exp2(float x){
  return __builtin_amdgcn_exp2f(x);
}
// async global->LDS, 16B per lane. LDS dest must be wave-uniform base + lane*16.
__device__ __forceinline__ void glds16(const unsigned short* g, unsigned short* l){
  __builtin_amdgcn_global_load_lds(
    (const __attribute__((address_space(1))) unsigned int*)g,
    (__attribute__((address_space(3))) unsigned int*)l, 16, 0, 0);
}

// ---------- convert X/Wq/Wk/Wv to bf16 + mask precompute, ONE launch ----------
__global__ void f2bf_all_kernel(const float* __restrict__ X,
                                const float* __restrict__ Wq,
                                const float* __restrict__ Wk,
                                const float* __restrict__ Wv,
                                const int* __restrict__ mask,
                                unsigned short* __restrict__ Xb,
                                unsigned short* __restrict__ Wb,
                                float* __restrict__ maskaddG,
                                unsigned int* __restrict__ flagsG){
  const int XQ = MROWS*HID/4;   // float4 quads in X
  const int WQ = HID*HID/4;     // per weight
  const int NB = (XQ + 3*WQ)/256;
  const int tid = threadIdx.x;
  if(blockIdx.x == NB){
    for(int i=tid;i<BATCH*SEQ;i+=256) maskaddG[i] = mask[i] ? 0.f : -1e30f;
    if(tid < 2) flagsG[tid] = 0u;
    __syncthreads();
    if(tid < BATCH*32){
      int b = tid >> 5, t = tid & 31;
      const int* mrow = mask + b*SEQ + t*64;
      int any = 0;
      for(int i=0;i<64;i++) any |= (mrow[i]==0);
      if(any) atomicOr(&flagsG[b], 1u << t);
    }
    return;
  }
  int i = blockIdx.x * 256 + tid;
  const float* src; unsigned short* dst; int off;
  if(i < XQ){ src = X; dst = Xb; off = i; }
  else {
    int j = i - XQ;
    int w = j / WQ; off = j - w*WQ;
    src = (w==0) ? Wq : (w==1) ? Wk : Wv;
    dst = Wb + (size_t)w*HID*HID;
  }
  float4 v = reinterpret_cast<const float4*>(src)[off];
  ushort4 o;
  o.x = f2bf(v.x); o.y = f2bf(v.y); o.z = f2bf(v.z); o.w = f2bf(v.w);
  reinterpret_cast<ushort4*>(dst)[off] = o;
}

// ---------- fused QKV projection GEMM (R7 version) ----------
__global__ __launch_bounds__(256) void qkv_gemm_kernel(
    const unsigned short* __restrict__ Xb,   // [4096][768]
    const unsigned short* __restrict__ Wb,   // [2304][768]
    const float* __restrict__ bq, const float* __restrict__ bk, const float* __restrict__ bv,
    unsigned short* __restrict__ Qb, unsigned short* __restrict__ Kb,
    unsigned short* __restrict__ Vtb)
{
  __shared__ __align__(16) union {
    struct { unsigned short A[2][128][32]; unsigned short B[2][128][32]; } s; // 32 KB
    unsigned short T[4][64][72];                                             // 36 KB (epilogue)
  } u;
  const int m0 = blockIdx.y << 7;
  const int n0 = blockIdx.x << 7;
  const int tid  = threadIdx.x;
  const int wave = tid >> 6, lane = tid & 63;
  const int wr = wave >> 1, wc = wave & 1;
  const int quad = lane >> 4, l15 = lane & 15;

  const unsigned short* gsrc[4];
  unsigned short* ldst[4];
  #pragma unroll
  for(int p=0;p<4;p++){
    int ck  = ((p&1)<<8) + tid;            // 0..511
    int row = ck>>2, c = ck&3, pc = c ^ (row&3);
    if(p<2){ gsrc[p] = Xb + (size_t)(m0+row)*HID + (pc<<3); ldst[p] = &u.s.A[0][row][c<<3]; }
    else   { gsrc[p] = Wb + (size_t)(n0+row)*HID + (pc<<3); ldst[p] = &u.s.B[0][row][c<<3]; }
  }

  floatx4 acc[4][4];
  #pragma unroll
  for(int i=0;i<4;i++)
    #pragma unroll
    for(int j=0;j<4;j++) acc[i][j] = (floatx4){0.f,0.f,0.f,0.f};

  auto stage = [&](int buf, int k0){
    const int bo = buf*(128*32);
    #pragma unroll
    for(int p=0;p<4;p++) glds16(gsrc[p] + k0, ldst[p] + bo);
  };

  stage(0, 0);
  __syncthreads();

  const int swa = l15 & 3;
  for(int t=0;t<HID/32;t++){
    const int buf = t & 1;
    if(t < HID/32 - 1) stage(buf^1, (t+1)*32);
    short8 a[4], b[4];
    #pragma unroll
    for(int i=0;i<4;i++)
      a[i] = *reinterpret_cast<const short8*>(&u.s.A[buf][wr*64+i*16+l15][(quad^swa)<<3]);
    #pragma unroll
    for(int j=0;j<4;j++)
      b[j] = *reinterpret_cast<const short8*>(&u.s.B[buf][wc*64+j*16+l15][(quad^swa)<<3]);
    #pragma unroll
    for(int i=0;i<4;i++)
      #pragma unroll
      for(int j=0;j<4;j++)
        acc[i][j] = __builtin_amdgcn_mfma_f32_16x16x32_bf16(a[i], b[j], acc[i][j], 0, 0, 0);
    __syncthreads();
  }

  // ---- epilogue; C layout col=lane&15 (n), row=quad*4+reg (m) ----
  const int which = n0 / HID;
  const int nbase = n0 - which*HID + wc*64;
  const int head  = nbase >> 6;
  const int b_    = m0 >> 11;
  const int hb    = head*BATCH + b_;
  const int s0    = (m0 & 2047) + wr*64;
  if(which < 2){
    unsigned short* dst = which==0 ? Qb : Kb;
    const float* bias = which==0 ? bq : bk;
    const float scale = which==0 ? QSCALE : 1.0f;
    #pragma unroll
    for(int j=0;j<4;j++){
      const float bb = bias[nbase + j*16 + l15];
      #pragma unroll
      for(int i=0;i<4;i++)
        #pragma unroll
        for(int r=0;r<4;r++)
          u.T[wave][i*16 + quad*4 + r][j*16 + l15] = f2bf((acc[i][j][r] + bb)*scale);
    }
    #pragma unroll
    for(int p=0;p<8;p++){
      const int row = p*8 + (lane>>3), dc = (lane&7)*8;
      uint4 v = *reinterpret_cast<const uint4*>(&u.T[wave][row][dc]);
      *reinterpret_cast<uint4*>(dst + ((size_t)(hb<<11) + s0 + row)*HS + dc) = v;
    }
  } else {
    #pragma unroll
    for(int j=0;j<4;j++){
      const float bb = bv[nbase + j*16 + l15];
      #pragma unroll
      for(int i=0;i<4;i++){
        uint2 pk;
        pk.x = f2bf2(acc[i][j][0]+bb, acc[i][j][1]+bb);
        pk.y = f2bf2(acc[i][j][2]+bb, acc[i][j][3]+bb);
        *reinterpret_cast<uint2*>(&u.T[wave][j*16+l15][i*16 + quad*4]) = pk;  // T[d][m]
      }
    }
    #pragma unroll
    for(int p=0;p<8;p++){
      const int d = p*8 + (lane>>3), cm = lane & 7;
      uint4 v = *reinterpret_cast<const uint4*>(&u.T[wave][d][cm*8]);
      *reinterpret_cast<uint4*>(Vtb + ((size_t)(hb*HS) + d)*SEQ + s0 + cm*8) = v;
    }
  }
}

// ---------- flash attention (R7 structure): no-max softmax, S^T, K+V LDS dbuf ----------
// grid HB*32; 64 q rows/block, 4 waves x 16 q rows; 1 barrier per 64-key tile;
// swizzled conflict-free LDS; packed-P via stride-68 Ps; raw v_exp_f32.
__global__ __launch_bounds__(256) void attn_kernel(
    const unsigned short* __restrict__ Qb,   // [hb][2048][64] (pre-scaled, log2 domain)
    const unsigned short* __restrict__ Kb,   // [hb][2048][64]
    const unsigned short* __restrict__ Vtb,  // [hb][64][2048]
    const float* __restrict__ maskaddG,      // [B][2048]
    const unsigned int* __restrict__ flagsG, // [B] bitmask of masked 64-key tiles
    float* __restrict__ out)                 // [B][2048][768]
{
  __shared__ __align__(16) unsigned short Ks2 [2][64][64];  // 16 KB
  __shared__ __align__(16) unsigned short Vts2[2][64][64];  // 16 KB
  __shared__ __align__(16) unsigned short Ps2 [4][16][68];  // 8.5 KB

  const int bid = blockIdx.x;
  const int hb = bid >> 5, qt = bid & 31, q0 = qt << 6;
  const int tid = threadIdx.x, wave = tid >> 6, lane = tid & 63;
  const int quad = lane >> 4, l15 = lane & 15;
  const int b_ = hb & 1, head = hb >> 1;

  // staging descriptors (chunk = p*256+tid; row=ck/8, c=ck%8, swizzle c^(row&7))
  const unsigned short* gK[2]; const unsigned short* gV[2];
  unsigned short* lK[2]; unsigned short* lV[2];
  #pragma unroll
  for(int p=0;p<2;p++){
    int ck = (p<<8) + tid;
    int row = ck>>3, c = ck&7, pc = c ^ (row&7);
    gK[p] = Kb  + ((size_t)(hb<<11) + row)*HS + (pc<<3);
    lK[p] = &Ks2[0][row][c<<3];
    gV[p] = Vtb + ((size_t)(hb*HS) + row)*SEQ + (pc<<3);
    lV[p] = &Vts2[0][row][c<<3];
  }
  auto stage = [&](int buf, int k0){
    const int bo = buf*(64*64);
    #pragma unroll
    for(int p=0;p<2;p++){
      glds16(gK[p] + (size_t)k0*HS, lK[p] + bo);
      glds16(gV[p] + k0,           lV[p] + bo);
    }
  };

  stage(0, 0);                               // async prefetch tile 0

  // Q fragments: direct b128 loads (scale folded in by GEMM)
  short8 a_q[2];
  {
    const unsigned short* qsrc = Qb + ((size_t)(hb<<11) + q0 + wave*16 + l15)*HS;
    a_q[0] = *reinterpret_cast<const short8*>(qsrc + quad*8);
    a_q[1] = *reinterpret_cast<const short8*>(qsrc + 32 + quad*8);
  }
  const unsigned int fl = flagsG[b_];        // per-tile masked bits, loaded ONCE

  float lsum4[4] = {0.f,0.f,0.f,0.f};
  floatx4 o_acc[4];
  #pragma unroll
  for(int dt=0;dt<4;dt++) o_acc[dt] = (floatx4){0.f,0.f,0.f,0.f};

  __syncthreads();                           // tile 0 staged

  const int sw = l15 & 7;
  for(int t=0;t<SEQ/64;t++){
    const int buf = t & 1, k0 = t << 6;
    if(t < SEQ/64 - 1) stage(buf^1, k0 + 64);   // async prefetch next tile

    const unsigned short (*Kst)[64] = Ks2[buf];
    const unsigned short (*Vst)[64] = Vts2[buf];

    // S^T: rows = keys (quad*4+r), cols = queries (l15)
    floatx4 st[4];
    #pragma unroll
    for(int kt=0;kt<4;kt++){
      st[kt] = (floatx4){0.f,0.f,0.f,0.f};
      #pragma unroll
      for(int c=0;c<2;c++){
        short8 kf = *reinterpret_cast<const short8*>(
            &Kst[kt*16 + l15][(((c<<2)+quad)^sw)<<3]);
        st[kt] = __builtin_amdgcn_mfma_f32_16x16x32_bf16(kf, a_q[c], st[kt], 0, 0, 0);
      }
    }

    // P = exp2(S [+ mask]) via raw v_exp_f32; rhu-pack; write P[q=l15][key] (2x b64)
    const bool masked = (fl >> t) & 1u;      // wave-uniform
    #pragma unroll
    for(int kt=0;kt<4;kt++){
      float p0,p1,p2,p3;
      if(!masked){
        p0 = fast_exp2(st[kt][0]); p1 = fast_exp2(st[kt][1]);
        p2 = fast_exp2(st[kt][2]); p3 = fast_exp2(st[kt][3]);
      } else {
        float4 ma = *reinterpret_cast<const float4*>(
            maskaddG + (b_<<11) + k0 + kt*16 + quad*4);
        p0 = fast_exp2(st[kt][0] + ma.x); p1 = fast_exp2(st[kt][1] + ma.y);
        p2 = fast_exp2(st[kt][2] + ma.z); p3 = fast_exp2(st[kt][3] + ma.w);
      }
      lsum4[0] += p0; lsum4[1] += p1; lsum4[2] += p2; lsum4[3] += p3;
      uint2 pk;
      pk.x = f2bf2_rhu(p0, p1);
      pk.y = f2bf2_rhu(p2, p3);
      *reinterpret_cast<uint2*>(&Ps2[wave][l15][kt*16 + quad*4]) = pk;
    }

    // A-frag read (same-wave RAW via lgkmcnt), then O += P V
    short8 ap0, ap1;
    {
      unsigned long long x0 = *reinterpret_cast<const unsigned long long*>(&Ps2[wave][l15][quad*8]);
      unsigned long long x1 = *reinterpret_cast<const unsigned long long*>(&Ps2[wave][l15][quad*8 + 4]);
      unsigned long long y0 = *reinterpret_cast<const unsigned long long*>(&Ps2[wave][l15][32 + quad*8]);
      unsigned long long y1 = *reinterpret_cast<const unsigned long long*>(&Ps2[wave][l15][32 + quad*8 + 4]);
      union { unsigned long long u[2]; short8 s; } cv0, cv1;
      cv0.u[0] = x0; cv0.u[1] = x1;
      cv1.u[0] = y0; cv1.u[1] = y1;
      ap0 = cv0.s; ap1 = cv1.s;
    }
    #pragma unroll
    for(int dt=0;dt<4;dt++){
      short8 bv0 = *reinterpret_cast<const short8*>(&Vst[dt*16 + l15][(quad^sw)<<3]);
      short8 bv1 = *reinterpret_cast<const short8*>(&Vst[dt*16 + l15][((4+quad)^sw)<<3]);
      o_acc[dt] = __builtin_amdgcn_mfma_f32_16x16x32_bf16(ap0, bv0, o_acc[dt], 0, 0, 0);
      o_acc[dt] = __builtin_amdgcn_mfma_f32_16x16x32_bf16(ap1, bv1, o_acc[dt], 0, 0, 0);
    }
    __syncthreads();   // staged t+1 drained; everyone done reading buf
  }

  // per-query row sum: lane holds q=l15 partial; reduce across quads, redistribute
  float lsum = (lsum4[0]+lsum4[1]) + (lsum4[2]+lsum4[3]);
  lsum += __shfl_xor(lsum, 16);
  lsum += __shfl_xor(lsum, 32);
  float linv[4];
  #pragma unroll
  for(int r=0;r<4;r++) linv[r] = 1.0f / __shfl(lsum, quad*4 + r);

  #pragma unroll
  for(int dt=0;dt<4;dt++){
    #pragma unroll
    for(int r=0;r<4;r++){
      const int srow = q0 + wave*16 + quad*4 + r;
      out[((size_t)(b_<<11) + srow)*HID + (head<<6) + dt*16 + l15] =
        o_acc[dt][r] * linv[r];
    }
  }
}

extern "C" void kernel_launch(void* const* d_in, const int* in_sizes, int n_in,
                              void* d_out, int out_size, void* d_ws, size_t ws_size,
                              hipStream_t stream) {
  const float* X    = (const float*)d_in[0];
  const int*   mask = (const int*)  d_in[1];
  const float* Wq   = (const float*)d_in[2];
  const float* bq   = (const float*)d_in[3];
  const float* Wk   = (const float*)d_in[4];
  const float* bk   = (const float*)d_in[5];
  const float* Wv   = (const float*)d_in[6];
  const float* bv   = (const float*)d_in[7];
  float* out = (float*)d_out;

  char* ws = (char*)d_ws;
  unsigned short* Xb  = (unsigned short*)ws;
  unsigned short* Wb  = Xb  + (size_t)MROWS*HID;
  unsigned short* Qb  = Wb  + (size_t)N3*HID;
  unsigned short* Kb  = Qb  + (size_t)HB*SEQ*HS;
  unsigned short* Vtb = Kb  + (size_t)HB*SEQ*HS;
  float* maskaddG = (float*)(Vtb + (size_t)HB*SEQ*HS);
  unsigned int* flagsG = (unsigned int*)(maskaddG + MROWS);

  const int total_quads = (MROWS*HID + 3*HID*HID)/4;
  f2bf_all_kernel<<<total_quads/256 + 1, 256, 0, stream>>>(
      X, Wq, Wk, Wv, mask, Xb, Wb, maskaddG, flagsG);

  qkv_gemm_kernel<<<dim3(N3/128, MROWS/128), 256, 0, stream>>>(
      Xb, Wb, bq, bk, bv, Qb, Kb, Vtb);

  attn_kernel<<<HB*32, 256, 0, stream>>>(
      Qb, Kb, Vtb, maskaddG, flagsG, out);
}

// Round 12
// 160.838 us; speedup vs baseline: 1.6616x; 1.0148x over previous
//
#include <hip/hip_runtime.h>
#include <hip/hip_bf16.h>

// Problem constants (B=2, S=2048, H=768, NH=12, HS=64)
#define BATCH 2
#define SEQ   2048
#define HID   768
#define NH    12
#define HS    64
#define MROWS (BATCH*SEQ)   // 4096
#define N3    (3*HID)       // 2304
#define HB    (NH*BATCH)    // 24

typedef __attribute__((ext_vector_type(8))) short short8;
typedef __attribute__((ext_vector_type(4))) short short4v;
typedef __attribute__((ext_vector_type(4))) float floatx4;

#ifndef __has_builtin
#define __has_builtin(x) 0
#endif
#if __has_builtin(__builtin_amdgcn_mfma_f32_16x16x16bf16_1k)
#define HAVE_K16 1
#else
#define HAVE_K16 0
#endif

// logits in log2 domain: Q pre-scaled by 0.125*log2(e) in GEMM epilogue
#define QSCALE 0.1803368801111204f

__device__ __forceinline__ unsigned short f2bf(float x){
  __hip_bfloat16 h = __float2bfloat16(x);
  return __builtin_bit_cast(unsigned short, h);
}
__device__ __forceinline__ unsigned int f2bf2(float lo, float hi){
  return (unsigned int)f2bf(lo) | ((unsigned int)f2bf(hi) << 16);
}
// pack two POSITIVE floats to bf16x2 with round-half-up: 2 adds + 1 v_perm
__device__ __forceinline__ unsigned int f2bf2_rhu(float lo, float hi){
  unsigned int a = __builtin_bit_cast(unsigned int, lo) + 0x8000u;
  unsigned int b = __builtin_bit_cast(unsigned int, hi) + 0x8000u;
  return __builtin_amdgcn_perm(b, a, 0x07060302u);  // [b.hi16 : a.hi16]
}
// raw v_exp_f32 (exp2): our domain needs no OCML edge-case expansion
__device__ __forceinline__ float fast_exp2(float x){
  return __builtin_amdgcn_exp2f(x);
}
// async global->LDS, 16B per lane. LDS dest must be wave-uniform base + lane*16.
__device__ __forceinline__ void glds16(const unsigned short* g, unsigned short* l){
  __builtin_amdgcn_global_load_lds(
    (const __attribute__((address_space(1))) unsigned int*)g,
    (__attribute__((address_space(3))) unsigned int*)l, 16, 0, 0);
}

// ---------- convert X/Wq/Wk/Wv to bf16 + mask precompute, ONE launch ----------
__global__ void f2bf_all_kernel(const float* __restrict__ X,
                                const float* __restrict__ Wq,
                                const float* __restrict__ Wk,
                                const float* __restrict__ Wv,
                                const int* __restrict__ mask,
                                unsigned short* __restrict__ Xb,
                                unsigned short* __restrict__ Wb,
                                float* __restrict__ maskaddG,
                                unsigned int* __restrict__ flagsG){
  const int XQ = MROWS*HID/4;   // float4 quads in X
  const int WQ = HID*HID/4;     // per weight
  const int NB = (XQ + 3*WQ)/256;
  const int tid = threadIdx.x;
  if(blockIdx.x == NB){
    for(int i=tid;i<BATCH*SEQ;i+=256) maskaddG[i] = mask[i] ? 0.f : -1e30f;
    if(tid < 2) flagsG[tid] = 0u;
    __syncthreads();
    if(tid < BATCH*32){
      int b = tid >> 5, t = tid & 31;
      const int* mrow = mask + b*SEQ + t*64;
      int any = 0;
      for(int i=0;i<64;i++) any |= (mrow[i]==0);
      if(any) atomicOr(&flagsG[b], 1u << t);
    }
    return;
  }
  int i = blockIdx.x * 256 + tid;
  const float* src; unsigned short* dst; int off;
  if(i < XQ){ src = X; dst = Xb; off = i; }
  else {
    int j = i - XQ;
    int w = j / WQ; off = j - w*WQ;
    src = (w==0) ? Wq : (w==1) ? Wk : Wv;
    dst = Wb + (size_t)w*HID*HID;
  }
  float4 v = reinterpret_cast<const float4*>(src)[off];
  ushort4 o;
  o.x = f2bf(v.x); o.y = f2bf(v.y); o.z = f2bf(v.z); o.w = f2bf(v.w);
  reinterpret_cast<ushort4*>(dst)[off] = o;
}

// ---------- fused QKV projection GEMM (unchanged from R11) ----------
__global__ __launch_bounds__(256) void qkv_gemm_kernel(
    const unsigned short* __restrict__ Xb,   // [4096][768]
    const unsigned short* __restrict__ Wb,   // [2304][768]
    const float* __restrict__ bq, const float* __restrict__ bk, const float* __restrict__ bv,
    unsigned short* __restrict__ Qb, unsigned short* __restrict__ Kb,
    unsigned short* __restrict__ Vtb)
{
  __shared__ __align__(16) union {
    struct { unsigned short A[2][128][32]; unsigned short B[2][128][32]; } s; // 32 KB
    unsigned short T[4][64][72];                                             // 36 KB (epilogue)
  } u;
  const int m0 = blockIdx.y << 7;
  const int n0 = blockIdx.x << 7;
  const int tid  = threadIdx.x;
  const int wave = tid >> 6, lane = tid & 63;
  const int wr = wave >> 1, wc = wave & 1;
  const int quad = lane >> 4, l15 = lane & 15;

  const unsigned short* gsrc[4];
  unsigned short* ldst[4];
  #pragma unroll
  for(int p=0;p<4;p++){
    int ck  = ((p&1)<<8) + tid;            // 0..511
    int row = ck>>2, c = ck&3, pc = c ^ (row&3);
    if(p<2){ gsrc[p] = Xb + (size_t)(m0+row)*HID + (pc<<3); ldst[p] = &u.s.A[0][row][c<<3]; }
    else   { gsrc[p] = Wb + (size_t)(n0+row)*HID + (pc<<3); ldst[p] = &u.s.B[0][row][c<<3]; }
  }

  floatx4 acc[4][4];
  #pragma unroll
  for(int i=0;i<4;i++)
    #pragma unroll
    for(int j=0;j<4;j++) acc[i][j] = (floatx4){0.f,0.f,0.f,0.f};

  auto stage = [&](int buf, int k0){
    const int bo = buf*(128*32);
    #pragma unroll
    for(int p=0;p<4;p++) glds16(gsrc[p] + k0, ldst[p] + bo);
  };

  stage(0, 0);
  __syncthreads();

  const int swa = l15 & 3;
  for(int t=0;t<HID/32;t++){
    const int buf = t & 1;
    if(t < HID/32 - 1) stage(buf^1, (t+1)*32);
    short8 a[4], b[4];
    #pragma unroll
    for(int i=0;i<4;i++)
      a[i] = *reinterpret_cast<const short8*>(&u.s.A[buf][wr*64+i*16+l15][(quad^swa)<<3]);
    #pragma unroll
    for(int j=0;j<4;j++)
      b[j] = *reinterpret_cast<const short8*>(&u.s.B[buf][wc*64+j*16+l15][(quad^swa)<<3]);
    #pragma unroll
    for(int i=0;i<4;i++)
      #pragma unroll
      for(int j=0;j<4;j++)
        acc[i][j] = __builtin_amdgcn_mfma_f32_16x16x32_bf16(a[i], b[j], acc[i][j], 0, 0, 0);
    __syncthreads();
  }

  // ---- epilogue; C layout col=lane&15 (n), row=quad*4+reg (m) ----
  const int which = n0 / HID;
  const int nbase = n0 - which*HID + wc*64;
  const int head  = nbase >> 6;
  const int b_    = m0 >> 11;
  const int hb    = head*BATCH + b_;
  const int s0    = (m0 & 2047) + wr*64;
  if(which < 2){
    unsigned short* dst = which==0 ? Qb : Kb;
    const float* bias = which==0 ? bq : bk;
    const float scale = which==0 ? QSCALE : 1.0f;
    #pragma unroll
    for(int j=0;j<4;j++){
      const float bb = bias[nbase + j*16 + l15];
      #pragma unroll
      for(int i=0;i<4;i++)
        #pragma unroll
        for(int r=0;r<4;r++)
          u.T[wave][i*16 + quad*4 + r][j*16 + l15] = f2bf((acc[i][j][r] + bb)*scale);
    }
    #pragma unroll
    for(int p=0;p<8;p++){
      const int row = p*8 + (lane>>3), dc = (lane&7)*8;
      uint4 v = *reinterpret_cast<const uint4*>(&u.T[wave][row][dc]);
      *reinterpret_cast<uint4*>(dst + ((size_t)(hb<<11) + s0 + row)*HS + dc) = v;
    }
  } else {
    #pragma unroll
    for(int j=0;j<4;j++){
      const float bb = bv[nbase + j*16 + l15];
      #pragma unroll
      for(int i=0;i<4;i++){
        uint2 pk;
        pk.x = f2bf2(acc[i][j][0]+bb, acc[i][j][1]+bb);
        pk.y = f2bf2(acc[i][j][2]+bb, acc[i][j][3]+bb);
        *reinterpret_cast<uint2*>(&u.T[wave][j*16+l15][i*16 + quad*4]) = pk;  // T[d][m]
      }
    }
    #pragma unroll
    for(int p=0;p<8;p++){
      const int d = p*8 + (lane>>3), cm = lane & 7;
      uint4 v = *reinterpret_cast<const uint4*>(&u.T[wave][d][cm*8]);
      *reinterpret_cast<uint4*>(Vtb + ((size_t)(hb*HS) + d)*SEQ + s0 + cm*8) = v;
    }
  }
}

#if HAVE_K16
// ---------- flash attention v2: waves split the KEY dim ----------
// Each wave: 16 keys x 64 q per tile. K reads 2xb128, V 4xb64 per wave-tile
// (was 16xb128): LDS pipe ~5x less. S^T C-layout == K=16 PV A-layout, so P
// never round-trips LDS. Per-wave partial O over its key subset; one-time
// cross-wave O reduction via LDS overlay at the end. No-max softmax.
__global__ __launch_bounds__(256, 3) void attn_kernel(
    const unsigned short* __restrict__ Qb,   // [hb][2048][64] (pre-scaled, log2 domain)
    const unsigned short* __restrict__ Kb,   // [hb][2048][64]
    const unsigned short* __restrict__ Vtb,  // [hb][64][2048]
    const float* __restrict__ maskaddG,      // [B][2048]
    const unsigned int* __restrict__ flagsG, // [B] bitmask of masked 64-key tiles
    float* __restrict__ out)                 // [B][2048][768]
{
  __shared__ __align__(16) union {
    struct { unsigned short K[2][64][64]; unsigned short V[2][64][64]; } s;  // 32 KB
    float Os[64][68];                                                        // 17.4 KB (epilogue)
  } sm;
  __shared__ float lsumS[4][64];

  const int bid = blockIdx.x;
  const int hb = bid >> 5, qt = bid & 31, q0 = qt << 6;
  const int tid = threadIdx.x, wave = tid >> 6, lane = tid & 63;
  const int quad = lane >> 4, l15 = lane & 15;
  const int b_ = hb & 1, head = hb >> 1;

  // staging descriptors (chunk = p*256+tid; row=ck/8, c=ck%8, swizzle c^(row&7))
  const unsigned short* gK[2]; const unsigned short* gV[2];
  unsigned short* lK[2]; unsigned short* lV[2];
  #pragma unroll
  for(int p=0;p<2;p++){
    int ck = (p<<8) + tid;
    int row = ck>>3, c = ck&7, pc = c ^ (row&7);
    gK[p] = Kb  + ((size_t)(hb<<11) + row)*HS + (pc<<3);
    lK[p] = &sm.s.K[0][row][c<<3];
    gV[p] = Vtb + ((size_t)(hb*HS) + row)*SEQ + (pc<<3);
    lV[p] = &sm.s.V[0][row][c<<3];
  }
  auto stage = [&](int buf, int k0){
    const int bo = buf*(64*64);
    #pragma unroll
    for(int p=0;p<2;p++){
      glds16(gK[p] + (size_t)k0*HS, lK[p] + bo);
      glds16(gV[p] + k0,           lV[p] + bo);
    }
  };

  stage(0, 0);                               // async prefetch tile 0

  // Q B-fragments for ALL 64 q rows (4 groups of 16), loaded once
  short8 a_q[4][2];
  #pragma unroll
  for(int f=0;f<4;f++){
    const unsigned short* qsrc = Qb + ((size_t)(hb<<11) + q0 + f*16 + l15)*HS;
    a_q[f][0] = *reinterpret_cast<const short8*>(qsrc + quad*8);
    a_q[f][1] = *reinterpret_cast<const short8*>(qsrc + 32 + quad*8);
  }
  const unsigned int fl = flagsG[b_];        // per-tile masked bits

  float lsum4[4] = {0.f,0.f,0.f,0.f};        // per q-group partial (this wave's keys)
  floatx4 o_acc[4][4];                       // [q-group f][d-group g]
  #pragma unroll
  for(int f=0;f<4;f++)
    #pragma unroll
    for(int g=0;g<4;g++) o_acc[f][g] = (floatx4){0.f,0.f,0.f,0.f};

  __syncthreads();                           // tile 0 staged

  const int sw = l15 & 7;
  const int krow = wave*16 + l15;            // this wave's K row slot in the tile
  const int vch = ((wave<<1) + (quad>>1)) ^ sw;   // swizzled V chunk for b64 read
  const int voff = (vch<<3) + ((quad&1)<<2);

  for(int t=0;t<SEQ/64;t++){
    const int buf = t & 1, k0 = t << 6;
    if(t < SEQ/64 - 1) stage(buf^1, k0 + 64);   // async prefetch next tile

    const unsigned short (*Kst)[64] = sm.s.K[buf];
    const unsigned short (*Vst)[64] = sm.s.V[buf];

    // K A-fragments: rows = this wave's 16 keys; 2 b128 reads total
    short8 kf0 = *reinterpret_cast<const short8*>(&Kst[krow][(quad^sw)<<3]);
    short8 kf1 = *reinterpret_cast<const short8*>(&Kst[krow][((4+quad)^sw)<<3]);

    // S^T[key16][q64]: 8 MFMAs (K=32); each kf feeds 4
    floatx4 st[4];
    #pragma unroll
    for(int f=0;f<4;f++) st[f] = (floatx4){0.f,0.f,0.f,0.f};
    #pragma unroll
    for(int f=0;f<4;f++) st[f] = __builtin_amdgcn_mfma_f32_16x16x32_bf16(kf0, a_q[f][0], st[f], 0, 0, 0);
    #pragma unroll
    for(int f=0;f<4;f++) st[f] = __builtin_amdgcn_mfma_f32_16x16x32_bf16(kf1, a_q[f][1], st[f], 0, 0, 0);

    // mask term for this wave's keys (key = k0 + wave*16 + quad*4 + r)
    float4 ma = (float4){0.f,0.f,0.f,0.f};
    if((fl >> t) & 1u)
      ma = *reinterpret_cast<const float4*>(maskaddG + (b_<<11) + k0 + wave*16 + quad*4);

    // P = exp2(S + ma), packed in-register: C-layout == K=16 A-layout, no LDS!
    short4v pA[4];
    #pragma unroll
    for(int f=0;f<4;f++){
      float p0 = fast_exp2(st[f][0] + ma.x);
      float p1 = fast_exp2(st[f][1] + ma.y);
      float p2 = fast_exp2(st[f][2] + ma.z);
      float p3 = fast_exp2(st[f][3] + ma.w);
      lsum4[f] += (p0+p1) + (p2+p3);
      union { unsigned int u[2]; short4v s; } pk;
      pk.u[0] = f2bf2_rhu(p0, p1);
      pk.u[1] = f2bf2_rhu(p2, p3);
      pA[f] = pk.s;
    }

    // O[f][g] += P V : V B-frags 4 b64 reads, 16 MFMAs (K=16)
    #pragma unroll
    for(int g=0;g<4;g++){
      short4v bvg = *reinterpret_cast<const short4v*>(&Vst[g*16 + l15][voff]);
      #pragma unroll
      for(int f=0;f<4;f++)
        o_acc[f][g] = __builtin_amdgcn_mfma_f32_16x16x16bf16_1k(pA[f], bvg, o_acc[f][g], 0, 0, 0);
    }
    __syncthreads();   // staged t+1 drained; everyone done reading buf
  }

  // lsum: reduce over quads (keys within wave), publish per wave
  #pragma unroll
  for(int f=0;f<4;f++){
    lsum4[f] += __shfl_xor(lsum4[f], 16);
    lsum4[f] += __shfl_xor(lsum4[f], 32);
  }
  if(lane < 16){
    #pragma unroll
    for(int f=0;f<4;f++) lsumS[wave][f*16 + lane] = lsum4[f];
  }

  // cross-wave O reduction in LDS overlay Os[d][q] (stride 68, b128 ops)
  // (loop's final __syncthreads guarantees all K/V reads are done)
  #pragma unroll
  for(int w=0;w<4;w++){
    if(wave == w){
      #pragma unroll
      for(int f=0;f<4;f++)
        #pragma unroll
        for(int g=0;g<4;g++){
          floatx4* dst = reinterpret_cast<floatx4*>(&sm.Os[g*16 + l15][f*16 + quad*4]);
          if(w == 0) *dst = o_acc[f][g];
          else      *dst = *dst + o_acc[f][g];
        }
    }
    __syncthreads();
  }

  // writeout: thread -> (q = tid/4, 16-d chunk), coalesced global stores
  {
    const int q = tid >> 2, dch = (tid & 3) << 4;
    const float linv = 1.0f /
      (lsumS[0][q] + lsumS[1][q] + lsumS[2][q] + lsumS[3][q]);
    float* orow = out + ((size_t)(b_<<11) + q0 + q)*HID + (head<<6) + dch;
    #pragma unroll
    for(int c4=0;c4<4;c4++){
      float4 o;
      o.x = sm.Os[dch + c4*4 + 0][q] * linv;
      o.y = sm.Os[dch + c4*4 + 1][q] * linv;
      o.z = sm.Os[dch + c4*4 + 2][q] * linv;
      o.w = sm.Os[dch + c4*4 + 3][q] * linv;
      reinterpret_cast<float4*>(orow)[c4] = o;
    }
  }
}
#else
// ---------- fallback: R11 attention (q-split waves, P via LDS) ----------
__global__ __launch_bounds__(256) void attn_kernel(
    const unsigned short* __restrict__ Qb,
    const unsigned short* __restrict__ Kb,
    const unsigned short* __restrict__ Vtb,
    const float* __restrict__ maskaddG,
    const unsigned int* __restrict__ flagsG,
    float* __restrict__ out)
{
  __shared__ __align__(16) unsigned short Ks2 [2][64][64];
  __shared__ __align__(16) unsigned short Vts2[2][64][64];
  __shared__ __align__(16) unsigned short Ps2 [4][16][68];

  const int bid = blockIdx.x;
  const int hb = bid >> 5, qt = bid & 31, q0 = qt << 6;
  const int tid = threadIdx.x, wave = tid >> 6, lane = tid & 63;
  const int quad = lane >> 4, l15 = lane & 15;
  const int b_ = hb & 1, head = hb >> 1;

  const unsigned short* gK[2]; const unsigned short* gV[2];
  unsigned short* lK[2]; unsigned short* lV[2];
  #pragma unroll
  for(int p=0;p<2;p++){
    int ck = (p<<8) + tid;
    int row = ck>>3, c = ck&7, pc = c ^ (row&7);
    gK[p] = Kb  + ((size_t)(hb<<11) + row)*HS + (pc<<3);
    lK[p] = &Ks2[0][row][c<<3];
    gV[p] = Vtb + ((size_t)(hb*HS) + row)*SEQ + (pc<<3);
    lV[p] = &Vts2[0][row][c<<3];
  }
  auto stage = [&](int buf, int k0){
    const int bo = buf*(64*64);
    #pragma unroll
    for(int p=0;p<2;p++){
      glds16(gK[p] + (size_t)k0*HS, lK[p] + bo);
      glds16(gV[p] + k0,           lV[p] + bo);
    }
  };

  stage(0, 0);
  short8 a_q[2];
  {
    const unsigned short* qsrc = Qb + ((size_t)(hb<<11) + q0 + wave*16 + l15)*HS;
    a_q[0] = *reinterpret_cast<const short8*>(qsrc + quad*8);
    a_q[1] = *reinterpret_cast<const short8*>(qsrc + 32 + quad*8);
  }
  const unsigned int fl = flagsG[b_];

  float lsum4[4] = {0.f,0.f,0.f,0.f};
  floatx4 o_acc[4];
  #pragma unroll
  for(int dt=0;dt<4;dt++) o_acc[dt] = (floatx4){0.f,0.f,0.f,0.f};

  __syncthreads();

  const int sw = l15 & 7;
  for(int t=0;t<SEQ/64;t++){
    const int buf = t & 1, k0 = t << 6;
    if(t < SEQ/64 - 1) stage(buf^1, k0 + 64);

    const unsigned short (*Kst)[64] = Ks2[buf];
    const unsigned short (*Vst)[64] = Vts2[buf];

    floatx4 st[4];
    #pragma unroll
    for(int kt=0;kt<4;kt++){
      st[kt] = (floatx4){0.f,0.f,0.f,0.f};
      #pragma unroll
      for(int c=0;c<2;c++){
        short8 kf = *reinterpret_cast<const short8*>(
            &Kst[kt*16 + l15][(((c<<2)+quad)^sw)<<3]);
        st[kt] = __builtin_amdgcn_mfma_f32_16x16x32_bf16(kf, a_q[c], st[kt], 0, 0, 0);
      }
    }

    const bool masked = (fl >> t) & 1u;
    #pragma unroll
    for(int kt=0;kt<4;kt++){
      float p0,p1,p2,p3;
      if(!masked){
        p0 = fast_exp2(st[kt][0]); p1 = fast_exp2(st[kt][1]);
        p2 = fast_exp2(st[kt][2]); p3 = fast_exp2(st[kt][3]);
      } else {
        float4 ma = *reinterpret_cast<const float4*>(
            maskaddG + (b_<<11) + k0 + kt*16 + quad*4);
        p0 = fast_exp2(st[kt][0] + ma.x); p1 = fast_exp2(st[kt][1] + ma.y);
        p2 = fast_exp2(st[kt][2] + ma.z); p3 = fast_exp2(st[kt][3] + ma.w);
      }
      lsum4[0] += p0; lsum4[1] += p1; lsum4[2] += p2; lsum4[3] += p3;
      uint2 pk;
      pk.x = f2bf2_rhu(p0, p1);
      pk.y = f2bf2_rhu(p2, p3);
      *reinterpret_cast<uint2*>(&Ps2[wave][l15][kt*16 + quad*4]) = pk;
    }

    short8 ap0, ap1;
    {
      unsigned long long x0 = *reinterpret_cast<const unsigned long long*>(&Ps2[wave][l15][quad*8]);
      unsigned long long x1 = *reinterpret_cast<const unsigned long long*>(&Ps2[wave][l15][quad*8 + 4]);
      unsigned long long y0 = *reinterpret_cast<const unsigned long long*>(&Ps2[wave][l15][32 + quad*8]);
      unsigned long long y1 = *reinterpret_cast<const unsigned long long*>(&Ps2[wave][l15][32 + quad*8 + 4]);
      union { unsigned long long u[2]; short8 s; } cv0, cv1;
      cv0.u[0] = x0; cv0.u[1] = x1;
      cv1.u[0] = y0; cv1.u[1] = y1;
      ap0 = cv0.s; ap1 = cv1.s;
    }
    #pragma unroll
    for(int dt=0;dt<4;dt++){
      short8 bv0 = *reinterpret_cast<const short8*>(&Vst[dt*16 + l15][(quad^sw)<<3]);
      short8 bv1 = *reinterpret_cast<const short8*>(&Vst[dt*16 + l15][((4+quad)^sw)<<3]);
      o_acc[dt] = __builtin_amdgcn_mfma_f32_16x16x32_bf16(ap0, bv0, o_acc[dt], 0, 0, 0);
      o_acc[dt] = __builtin_amdgcn_mfma_f32_16x16x32_bf16(ap1, bv1, o_acc[dt], 0, 0, 0);
    }
    __syncthreads();
  }

  float lsum = (lsum4[0]+lsum4[1]) + (lsum4[2]+lsum4[3]);
  lsum += __shfl_xor(lsum, 16);
  lsum += __shfl_xor(lsum, 32);
  float linv[4];
  #pragma unroll
  for(int r=0;r<4;r++) linv[r] = 1.0f / __shfl(lsum, quad*4 + r);

  #pragma unroll
  for(int dt=0;dt<4;dt++){
    #pragma unroll
    for(int r=0;r<4;r++){
      const int srow = q0 + wave*16 + quad*4 + r;
      out[((size_t)(b_<<11) + srow)*HID + (head<<6) + dt*16 + l15] =
        o_acc[dt][r] * linv[r];
    }
  }
}
#endif

extern "C" void kernel_launch(void* const* d_in, const int* in_sizes, int n_in,
                              void* d_out, int out_size, void* d_ws, size_t ws_size,
                              hipStream_t stream) {
  const float* X    = (const float*)d_in[0];
  const int*   mask = (const int*)  d_in[1];
  const float* Wq   = (const float*)d_in[2];
  const float* bq   = (const float*)d_in[3];
  const float* Wk   = (const float*)d_in[4];
  const float* bk   = (const float*)d_in[5];
  const float* Wv   = (const float*)d_in[6];
  const float* bv   = (const float*)d_in[7];
  float* out = (float*)d_out;

  char* ws = (char*)d_ws;
  unsigned short* Xb  = (unsigned short*)ws;
  unsigned short* Wb  = Xb  + (size_t)MROWS*HID;
  unsigned short* Qb  = Wb  + (size_t)N3*HID;
  unsigned short* Kb  = Qb  + (size_t)HB*SEQ*HS;
  unsigned short* Vtb = Kb  + (size_t)HB*SEQ*HS;
  float* maskaddG = (float*)(Vtb + (size_t)HB*SEQ*HS);
  unsigned int* flagsG = (unsigned int*)(maskaddG + MROWS);

  const int total_quads = (MROWS*HID + 3*HID*HID)/4;
  f2bf_all_kernel<<<total_quads/256 + 1, 256, 0, stream>>>(
      X, Wq, Wk, Wv, mask, Xb, Wb, maskaddG, flagsG);

  qkv_gemm_kernel<<<dim3(N3/128, MROWS/128), 256, 0, stream>>>(
      Xb, Wb, bq, bk, bv, Qb, Kb, Vtb);

  attn_kernel<<<HB*32, 256, 0, stream>>>(
      Qb, Kb, Vtb, maskaddG, flagsG, out);
}